// Round 3
// baseline (65.890 us; speedup 1.0000x reference)
//
#include <hip/hip_runtime.h>

// BS=16, SQ=128, NQ=21, NK=7, D=256
// softmax over a size-1 axis == 1.0 identically, so:
//   Output 0: attn_out (16,128,21,7,256) = keys broadcast 21x over q
//   Output 1: attn_weights (16,128,21,7,1) == 1.0
// d_out layout: [attn_out 77,070,336 fp32][attn_weights 301,056 fp32]

#define NBS     2048    // BS*SQ — one block per (b,s)
#define NKD4    448     // NK*D/4 = 7*256/4 float4 per key row (1 per thread)
#define NQ_     21
#define ONES_PER_BLK 147  // 301,056 floats / 2048 blocks

typedef float vfloat4 __attribute__((ext_vector_type(4)));

__global__ __launch_bounds__(448) void bahdanau_bcast_kernel(
    const vfloat4* __restrict__ keys, vfloat4* __restrict__ out,
    float* __restrict__ ones) {
    const int b = blockIdx.x;
    const int t = threadIdx.x;

    // read key row once into register, store 21 copies (1 KiB/wave/store, nt)
    const vfloat4 v = keys[(size_t)b * NKD4 + t];
    vfloat4* dst = out + (size_t)b * (NQ_ * NKD4) + t;
    #pragma unroll
    for (int q = 0; q < NQ_; ++q) {
        __builtin_nontemporal_store(v, dst + (size_t)q * NKD4);
    }

    // this block's even share of the all-ones weights output
    if (t < ONES_PER_BLK) {
        __builtin_nontemporal_store(1.0f, ones + b * ONES_PER_BLK + t);
    }
}

extern "C" void kernel_launch(void* const* d_in, const int* in_sizes, int n_in,
                              void* d_out, int out_size, void* d_ws, size_t ws_size,
                              hipStream_t stream) {
    const vfloat4* keys = (const vfloat4*)d_in[1];        // (16,128,1,7,256) fp32
    vfloat4* out = (vfloat4*)d_out;                       // attn_out region
    float* ones = (float*)d_out + (size_t)77070336;       // attn_weights region
    hipLaunchKernelGGL(bahdanau_bcast_kernel,
                       dim3(NBS), dim3(NKD4), 0, stream,
                       keys, out, ones);
}

// Round 4
// 60.178 us; speedup vs baseline: 1.0949x; 1.0949x over previous
//
#include <hip/hip_runtime.h>

// BS=16, SQ=128, NQ=21, NK=7, D=256
// softmax over a size-1 axis == 1.0 identically, so:
//   Output 0: attn_out (16,128,21,7,256) = keys broadcast 21x over q
//   Output 1: attn_weights (16,128,21,7,1) == 1.0
// d_out layout: [attn_out 77,070,336 fp32][attn_weights 301,056 fp32]
//
// R3 post-mortem: nontemporal stores REGRESSED (60.4 -> ~64 us normalized).
// Normal stores let L2 absorb/stream the write; keep them.

#define NBS     2048    // BS*SQ — one block per (b,s); 2048 = 8*256 CUs, even
#define NKD4    448     // NK*D/4 = 7*256/4 float4 per key row (1 per thread)
#define NQ_     21
#define ONES_PER_BLK 147  // 301,056 floats / 2048 blocks

typedef float vfloat4 __attribute__((ext_vector_type(4)));

__global__ __launch_bounds__(448) void bahdanau_bcast_kernel(
    const vfloat4* __restrict__ keys, vfloat4* __restrict__ out,
    float* __restrict__ ones) {
    const int b = blockIdx.x;
    const int t = threadIdx.x;

    // read key row once into register, store 21 copies (1 KiB/wave/store)
    const vfloat4 v = keys[(size_t)b * NKD4 + t];
    vfloat4* dst = out + (size_t)b * (NQ_ * NKD4) + t;
    #pragma unroll
    for (int q = 0; q < NQ_; ++q) {
        dst[(size_t)q * NKD4] = v;
    }

    // this block's even share of the all-ones weights output
    if (t < ONES_PER_BLK) {
        ones[b * ONES_PER_BLK + t] = 1.0f;
    }
}

extern "C" void kernel_launch(void* const* d_in, const int* in_sizes, int n_in,
                              void* d_out, int out_size, void* d_ws, size_t ws_size,
                              hipStream_t stream) {
    const vfloat4* keys = (const vfloat4*)d_in[1];        // (16,128,1,7,256) fp32
    vfloat4* out = (vfloat4*)d_out;                       // attn_out region
    float* ones = (float*)d_out + (size_t)77070336;       // attn_weights region
    hipLaunchKernelGGL(bahdanau_bcast_kernel,
                       dim3(NBS), dim3(NKD4), 0, stream,
                       keys, out, ones);
}